// Round 19
// baseline (265.370 us; speedup 1.0000x reference)
//
#include <hip/hip_runtime.h>
#include <stdint.h>

// GroupedLinear: y[b, g*256+o] = sum_i x[b, g*256+i] * W[g,o,i] + bias[g,o]
// B=8192, G=16, GIN=GOUT=256. fp32 in/out, bf16 MFMA compute.
//
// Evidence ladder: v7 (64-tile, bad order) 119us @ 404 MB HBM; v8 (64-tile,
// supertile order) 104us @ 204 MB -- identical instructions, nearer caches,
// time ~flat => NOT latency/HBM-bound. Limiter = bytes through the VGPR
// stage path: 64-tile stages nblocks*(BM+BN)*K*4B = 1 GB @ ~16 B/cy/CU = 102us.
// v9: halve staged bytes (128-tile -> 512 MB) while keeping v8's supertile
// L2 locality and raising occupancy to 4 blocks/CU (32 KB LDS single-buf,
// ~124 total regs, waves_per_eu(4)). Target ~60-70us.

#define IN_F   4096
#define OUT_F  4096
#define GIN    256
#define GOUT   256

#define BM 128
#define BN 128
#define BK 64
#define KTOT 256

using short8  = __attribute__((ext_vector_type(8))) short;
using floatx4 = __attribute__((ext_vector_type(4))) float;

// round-to-nearest-even fp32 -> bf16 (branch-free)
__device__ __forceinline__ short f2bf_rne(float f) {
    unsigned u = __builtin_bit_cast(unsigned, f);
    unsigned r = u + 0x7FFFu + ((u >> 16) & 1u);
    return (short)(r >> 16);
}

__device__ __forceinline__ short8 pack8(floatx4 f0, floatx4 f1) {
    short8 p;
    p[0] = f2bf_rne(f0[0]); p[1] = f2bf_rne(f0[1]);
    p[2] = f2bf_rne(f0[2]); p[3] = f2bf_rne(f0[3]);
    p[4] = f2bf_rne(f1[0]); p[5] = f2bf_rne(f1[1]);
    p[6] = f2bf_rne(f1[2]); p[7] = f2bf_rne(f1[3]);
    return p;
}

// lgkm-only barrier: staging's global loads are consumed by pack8 before
// ds_write (data dep), so only ds ops need draining at the barrier.
// sched_barrier per rule #18. Proven correct v3/v6/v7/v8.
#define SYNC_PHASE() do {                                        \
    asm volatile("s_waitcnt lgkmcnt(0)" ::: "memory");           \
    __builtin_amdgcn_sched_barrier(0);                           \
    __builtin_amdgcn_s_barrier();                                \
    __builtin_amdgcn_sched_barrier(0);                           \
} while (0)

__global__ __launch_bounds__(256) __attribute__((amdgpu_waves_per_eu(4)))
void grouped_linear_kernel(const float* __restrict__ X,
                           const float* __restrict__ W,
                           const float* __restrict__ Bias,
                           float* __restrict__ Out) {
    // bf16 LDS tiles, XOR-swizzled in 8-elem (16B) chunks: chunk q of row r
    // at q ^ (r&7) -> conflict-free ds_write_b128 / ds_read_b128 (0 measured
    // across v0-v8). Single-buffered 32 KB -> 4 blocks/CU (reg-capped).
    __shared__ __align__(16) short lsA[BM * BK];   // 16 KB
    __shared__ __align__(16) short lsB[BN * BK];   // 16 KB

    const int t    = threadIdx.x;
    const int lane = t & 63;
    const int wave = t >> 6;
    const int wm   = wave >> 1;     // wave row (0..1) -> 64 rows
    const int wn   = wave & 1;      // wave col (0..1) -> 64 cols
    const int lrow = lane & 15;
    const int quad = lane >> 4;     // 0..3

    // XCD supertile swizzle (v8-proven, adapted to 128-tile). 2048 blocks;
    // xcd = bid&7 (HW round-robin) covers bn in [4*xcd, 4*xcd+4) = 2 groups.
    // Within XCD: supertile = 8 bm x 4 bn (32 blocks); X-panel sharers
    // (2 bn of one group, same bm) are 8 blocks apart -> L2-co-resident;
    // supertile footprint = 2 MB X + 512 KB W < 4 MB L2; W L2-resident.
    const int bid   = blockIdx.x;
    const int xcd   = bid & 7;
    const int idx   = bid >> 3;          // 0..255 within XCD
    const int bmblk = idx >> 5;          // 0..7   supertile row
    const int bn_l  = (idx >> 3) & 3;    // 0..3   bn within XCD
    const int bm_i  = idx & 7;           // 0..7   bm within supertile
    const int bn    = xcd * 4 + bn_l;    // 0..31 col-tiles of 128
    const int bm    = bmblk * 8 + bm_i;  // 0..63 row-tiles of 128

    const int g    = bn >> 1;            // group (2 col-tiles per group)
    const int row0 = bm * BM;
    const int col0 = bn * BN;
    const int nlb  = (bn & 1) * BN;      // N offset inside this group's W

    const float* Wg = W + (size_t)g * GOUT * GIN + (size_t)nlb * GIN;
    const float* Xg = X + (size_t)row0 * IN_F + g * GIN;

    floatx4 acc[4][4];
    #pragma unroll
    for (int i = 0; i < 4; ++i)
        #pragma unroll
        for (int j = 0; j < 4; ++j)
            acc[i][j] = (floatx4){0.f, 0.f, 0.f, 0.f};

    // staging geometry: 8 threads cover one 64-float row (32B/lane);
    // 256 threads = 32 rows/pass, 4 passes per 128-row tile.
    const int c8 = (t & 7) * 8;     // float offset in the 64-wide K slice
    const int q0 = (t & 7);
    const int r0 = (t >> 3);        // 0..31

    for (int kt = 0; kt < KTOT / BK; ++kt) {
        const int kbase = kt * BK;

        // ---- stage A (x) and B (W): fp32 -> bf16 LDS, swizzled ----
        #pragma unroll
        for (int it = 0; it < 4; ++it) {
            int r = r0 + 32 * it;                        // 0..127
            const float* src = Xg + (size_t)r * IN_F + kbase + c8;
            floatx4 f0 = *(const floatx4*)src;
            floatx4 f1 = *(const floatx4*)(src + 4);
            int q = q0 ^ (r & 7);
            *(short8*)&lsA[r * BK + q * 8] = pack8(f0, f1);
        }
        #pragma unroll
        for (int it = 0; it < 4; ++it) {
            int n = r0 + 32 * it;                        // 0..127
            const float* src = Wg + (size_t)n * GIN + kbase + c8;
            floatx4 f0 = *(const floatx4*)src;
            floatx4 f1 = *(const floatx4*)(src + 4);
            int q = q0 ^ (n & 7);
            *(short8*)&lsB[n * BK + q * 8] = pack8(f0, f1);
        }
        SYNC_PHASE();

        // ---- compute: 2 MFMA K-substeps of 32, 4x4 frags ----
        #pragma unroll
        for (int kk = 0; kk < 2; ++kk) {
            int qs = kk * 4 + quad;                      // chunk index 0..7
            short8 a[4], b[4];
            #pragma unroll
            for (int i = 0; i < 4; ++i) {
                int r = wm * 64 + i * 16 + lrow;
                a[i] = *(const short8*)&lsA[r * BK + ((qs ^ (r & 7)) * 8)];
            }
            #pragma unroll
            for (int j = 0; j < 4; ++j) {
                int n = wn * 64 + j * 16 + lrow;
                b[j] = *(const short8*)&lsB[n * BK + ((qs ^ (n & 7)) * 8)];
            }
            #pragma unroll
            for (int i = 0; i < 4; ++i)
                #pragma unroll
                for (int j = 0; j < 4; ++j)
                    acc[i][j] = __builtin_amdgcn_mfma_f32_16x16x32_bf16(
                        a[i], b[j], acc[i][j], 0, 0, 0);
        }
        SYNC_PHASE();
    }

    // ---- epilogue: C/D layout col=lane&15, row=quad*4+reg; add bias ----
    #pragma unroll
    for (int j = 0; j < 4; ++j) {
        int gc = col0 + wn * 64 + j * 16 + lrow;   // global out column
        float bias = Bias[gc];
        #pragma unroll
        for (int i = 0; i < 4; ++i) {
            int gr = row0 + wm * 64 + i * 16 + quad * 4;
            floatx4 v = acc[i][j];
            #pragma unroll
            for (int rg = 0; rg < 4; ++rg)
                Out[(size_t)(gr + rg) * OUT_F + gc] = v[rg] + bias;
        }
    }
}

extern "C" void kernel_launch(void* const* d_in, const int* in_sizes, int n_in,
                              void* d_out, int out_size, void* d_ws, size_t ws_size,
                              hipStream_t stream) {
    const float* X    = (const float*)d_in[0];   // [8192, 4096]
    const float* W    = (const float*)d_in[1];   // [16, 256, 256]
    const float* Bias = (const float*)d_in[2];   // [16, 256]
    float*       Out  = (float*)d_out;           // [8192, 4096]

    dim3 grid(64 * 32);   // 64 M-tiles x 32 N-tiles of 128x128
    dim3 block(256);
    grouped_linear_kernel<<<grid, block, 0, stream>>>(X, W, Bias, Out);
}

// Round 20
// 248.888 us; speedup vs baseline: 1.0662x; 1.0662x over previous
//
#include <hip/hip_runtime.h>
#include <stdint.h>

// GroupedLinear: y[b, g*256+o] = sum_i x[b, g*256+i] * W[g,o,i] + bias[g,o]
// B=8192, G=16, GIN=GOUT=256. fp32 in/out, bf16 MFMA compute.
//
// Model (v0-v9 evidence): stage-path throughput scales with resident waves,
// not bytes: 12 waves -> 5.2 TB/s (v9), 22 waves -> 9.8 TB/s (v8). Staged
// bytes scale with 1/tile. v9 = 512 MB @ 5.2 = 98us; v8 = 1 GB @ 9.8 = 104us.
// v10: keep 128^2 (512 MB staged, FETCH 70 MB proven) but 512-thread blocks:
// per-wave tile 64x32 -> acc 32 regs, ~70 total -> waves_per_eu(6) fits ->
// 3 blocks x 8 waves = 24 waves/CU (75%), 2x v9's TLP. Target 512/8.5 ~ 60us.
// LDS 20 KB: BK=32, rows padded to 40 shorts (80 B) -> 8-way row-bank spread,
// no XOR needed. Supertile order unchanged (v8/v9-proven).

#define IN_F   4096
#define OUT_F  4096
#define GIN    256
#define GOUT   256

#define BM 128
#define BN 128
#define BK 32
#define KTOT 256
#define LROW 40   // LDS row stride in shorts (32 bf16 + 8 pad) = 80 B

using short8  = __attribute__((ext_vector_type(8))) short;
using floatx4 = __attribute__((ext_vector_type(4))) float;

// round-to-nearest-even fp32 -> bf16 (branch-free)
__device__ __forceinline__ short f2bf_rne(float f) {
    unsigned u = __builtin_bit_cast(unsigned, f);
    unsigned r = u + 0x7FFFu + ((u >> 16) & 1u);
    return (short)(r >> 16);
}

__device__ __forceinline__ short8 pack8(floatx4 f0, floatx4 f1) {
    short8 p;
    p[0] = f2bf_rne(f0[0]); p[1] = f2bf_rne(f0[1]);
    p[2] = f2bf_rne(f0[2]); p[3] = f2bf_rne(f0[3]);
    p[4] = f2bf_rne(f1[0]); p[5] = f2bf_rne(f1[1]);
    p[6] = f2bf_rne(f1[2]); p[7] = f2bf_rne(f1[3]);
    return p;
}

// lgkm-only barrier (global loads consumed by pack8 before ds_write, so only
// ds ops need draining). sched_barrier per rule #18. Proven v3-v9.
#define SYNC_PHASE() do {                                        \
    asm volatile("s_waitcnt lgkmcnt(0)" ::: "memory");           \
    __builtin_amdgcn_sched_barrier(0);                           \
    __builtin_amdgcn_s_barrier();                                \
    __builtin_amdgcn_sched_barrier(0);                           \
} while (0)

__global__ __launch_bounds__(512) __attribute__((amdgpu_waves_per_eu(6)))
void grouped_linear_kernel(const float* __restrict__ X,
                           const float* __restrict__ W,
                           const float* __restrict__ Bias,
                           float* __restrict__ Out) {
    __shared__ __align__(16) short lsA[BM * LROW];   // 10 KB
    __shared__ __align__(16) short lsB[BN * LROW];   // 10 KB

    const int t    = threadIdx.x;
    const int lane = t & 63;
    const int wave = t >> 6;        // 0..7
    const int wm   = wave >> 2;     // 0..1 -> 64-row half
    const int wn   = wave & 3;      // 0..3 -> 32-col quarter
    const int lrow = lane & 15;
    const int quad = lane >> 4;     // 0..3 -> k-offset quad*8

    // XCD supertile swizzle (v8/v9-proven, FETCH 70 MB). 2048 blocks;
    // xcd = bid&7 covers bn in [4*xcd,4*xcd+4) = 2 groups; within XCD
    // supertile = 8 bm x 4 bn; X-panel sharers 8 blocks apart.
    const int bid   = blockIdx.x;
    const int xcd   = bid & 7;
    const int idx   = bid >> 3;          // 0..255 within XCD
    const int bmblk = idx >> 5;          // 0..7   supertile row
    const int bn_l  = (idx >> 3) & 3;    // 0..3   bn within XCD
    const int bm_i  = idx & 7;           // 0..7   bm within supertile
    const int bn    = xcd * 4 + bn_l;    // 0..31
    const int bm    = bmblk * 8 + bm_i;  // 0..63

    const int g    = bn >> 1;
    const int row0 = bm * BM;
    const int col0 = bn * BN;
    const int nlb  = (bn & 1) * BN;

    const float* Wg = W + (size_t)g * GOUT * GIN + (size_t)nlb * GIN;
    const float* Xg = X + (size_t)row0 * IN_F + g * GIN;

    floatx4 acc[4][2];
    #pragma unroll
    for (int i = 0; i < 4; ++i)
        #pragma unroll
        for (int j = 0; j < 2; ++j)
            acc[i][j] = (floatx4){0.f, 0.f, 0.f, 0.f};

    // staging geometry: 4 threads cover one 32-float row (8 floats each);
    // 512 threads = 128 rows in ONE pass per tile.
    const int c8 = (t & 3) * 8;     // float offset in the 32-wide K slice
    const int r0 = (t >> 2);        // 0..127

    for (int kt = 0; kt < KTOT / BK; ++kt) {   // 8 steps
        const int kbase = kt * BK;

        // ---- stage A (x) and B (W): fp32 -> bf16 LDS, padded rows ----
        {
            const float* srcA = Xg + (size_t)r0 * IN_F + kbase + c8;
            floatx4 a0 = *(const floatx4*)srcA;
            floatx4 a1 = *(const floatx4*)(srcA + 4);
            const float* srcB = Wg + (size_t)r0 * GIN + kbase + c8;
            floatx4 b0 = *(const floatx4*)srcB;
            floatx4 b1 = *(const floatx4*)(srcB + 4);
            *(short8*)&lsA[r0 * LROW + c8] = pack8(a0, a1);
            *(short8*)&lsB[r0 * LROW + c8] = pack8(b0, b1);
        }
        SYNC_PHASE();

        // ---- compute: BK=32 = one MFMA K-chunk; 4x2 frags ----
        short8 a[4], b[2];
        #pragma unroll
        for (int i = 0; i < 4; ++i) {
            int r = wm * 64 + i * 16 + lrow;
            a[i] = *(const short8*)&lsA[r * LROW + quad * 8];
        }
        #pragma unroll
        for (int j = 0; j < 2; ++j) {
            int n = wn * 32 + j * 16 + lrow;
            b[j] = *(const short8*)&lsB[n * LROW + quad * 8];
        }
        #pragma unroll
        for (int i = 0; i < 4; ++i)
            #pragma unroll
            for (int j = 0; j < 2; ++j)
                acc[i][j] = __builtin_amdgcn_mfma_f32_16x16x32_bf16(
                    a[i], b[j], acc[i][j], 0, 0, 0);
        SYNC_PHASE();
    }

    // ---- epilogue: C/D layout col=lane&15, row=quad*4+reg; add bias ----
    #pragma unroll
    for (int j = 0; j < 2; ++j) {
        int gc = col0 + wn * 32 + j * 16 + lrow;
        float bias = Bias[gc];
        #pragma unroll
        for (int i = 0; i < 4; ++i) {
            int gr = row0 + wm * 64 + i * 16 + quad * 4;
            floatx4 v = acc[i][j];
            #pragma unroll
            for (int rg = 0; rg < 4; ++rg)
                Out[(size_t)(gr + rg) * OUT_F + gc] = v[rg] + bias;
        }
    }
}

extern "C" void kernel_launch(void* const* d_in, const int* in_sizes, int n_in,
                              void* d_out, int out_size, void* d_ws, size_t ws_size,
                              hipStream_t stream) {
    const float* X    = (const float*)d_in[0];   // [8192, 4096]
    const float* W    = (const float*)d_in[1];   // [16, 256, 256]
    const float* Bias = (const float*)d_in[2];   // [16, 256]
    float*       Out  = (float*)d_out;           // [8192, 4096]

    dim3 grid(64 * 32);   // 64 M-tiles x 32 N-tiles of 128x128
    dim3 block(512);
    grouped_linear_kernel<<<grid, block, 0, stream>>>(X, W, Bias, Out);
}